// Round 2
// baseline (752.400 us; speedup 1.0000x reference)
//
#include <hip/hip_runtime.h>
#include <cstddef>

#define NEV   4096
#define NPAIR 32768
#define NEDGE (2*NPAIR)
#define EDIM  768
#define CDIM  256
#define MLPH  1024
#define LLEN  256

// ---------------------------------------------------------------- utilities
__global__ void k_zero(int* __restrict__ deg, float* __restrict__ out) {
  int i = blockIdx.x * 256 + threadIdx.x;
  if (i < NEV) deg[i] = 0;
  if (i == 0) out[0] = 0.f;
}

// ---------------------------------------------------------------- e_emb: masked span mean
__global__ void k_embed(const float* __restrict__ sent, const int* __restrict__ es,
                        const int* __restrict__ st, const int* __restrict__ en,
                        float* __restrict__ e_emb) {
  int node = blockIdx.x;
  int s = es[node];
  int a = st[node];
  int span = en[node] - a;
  float fspan = (float)span;
  const float* base = sent + ((size_t)s * LLEN + a) * EDIM;
  for (int d = threadIdx.x; d < EDIM; d += 256) {
    float acc = 0.f;
    for (int m = 0; m < span; ++m) acc += base[(size_t)m * EDIM + d];
    e_emb[(size_t)node * EDIM + d] = acc / fspan;
  }
}

// ---------------------------------------------------------------- CSR build (dst_all = [p1; p0])
__global__ void k_count(const int* __restrict__ pair, int* __restrict__ deg) {
  int e = blockIdx.x * 256 + threadIdx.x;
  if (e >= NEDGE) return;
  int p = (e < NPAIR) ? e : e - NPAIR;
  int dst = (e < NPAIR) ? pair[2 * p + 1] : pair[2 * p];
  atomicAdd(&deg[dst], 1);
}

__global__ void k_scan(const int* __restrict__ deg, int* __restrict__ rowp,
                       int* __restrict__ cursor) {
  __shared__ int part[256];
  int t = threadIdx.x;
  int base = t * 16;
  int sum = 0;
  for (int i = 0; i < 16; ++i) sum += deg[base + i];
  part[t] = sum;
  __syncthreads();
  for (int off = 1; off < 256; off <<= 1) {
    int v = (t >= off) ? part[t - off] : 0;
    __syncthreads();
    part[t] += v;
    __syncthreads();
  }
  int run = (t == 0) ? 0 : part[t - 1];
  for (int i = 0; i < 16; ++i) {
    rowp[base + i] = run;
    cursor[base + i] = 0;
    run += deg[base + i];
  }
  if (t == 255) rowp[NEV] = run;
}

__global__ void k_scatter(const int* __restrict__ pair, const int* __restrict__ rowp,
                          int* __restrict__ cursor, int* __restrict__ e_src,
                          int* __restrict__ e_id) {
  int e = blockIdx.x * 256 + threadIdx.x;
  if (e >= NEDGE) return;
  int p   = (e < NPAIR) ? e : e - NPAIR;
  int src = (e < NPAIR) ? pair[2 * p]     : pair[2 * p + 1];
  int dst = (e < NPAIR) ? pair[2 * p + 1] : pair[2 * p];
  int pos = rowp[dst] + atomicAdd(&cursor[dst], 1);
  e_src[pos] = src;
  e_id[pos]  = e;
}

// ---------------------------------------------------------------- fp32 GEMM 64x64x16, 4x4/thread
// C[M x Ncols] = A[M x K] @ B[K x Ncols] (+bias). Grid: (Ncols/64, M/64). M%64==0, Ncols%64==0, K%16==0.
__global__ __launch_bounds__(256) void sgemm64(
    const float* __restrict__ A, const float* __restrict__ B,
    float* __restrict__ C, const float* __restrict__ bias,
    int K, int lda, int ldb, int ldc)
{
  __shared__ float As[16][68];
  __shared__ float Bs[16][68];
  int tid = threadIdx.x;
  int brow = blockIdx.y * 64;
  int bcol = blockIdx.x * 64;
  int tr = tid >> 4;
  int tc = tid & 15;
  int a_row = tid >> 2;
  int a_c4  = (tid & 3) << 2;
  int b_row = tid >> 4;
  int b_c4  = (tid & 15) << 2;
  float acc[4][4] = {};
  for (int k0 = 0; k0 < K; k0 += 16) {
    float4 av = *(const float4*)(A + (size_t)(brow + a_row) * lda + k0 + a_c4);
    As[a_c4 + 0][a_row] = av.x;
    As[a_c4 + 1][a_row] = av.y;
    As[a_c4 + 2][a_row] = av.z;
    As[a_c4 + 3][a_row] = av.w;
    *(float4*)&Bs[b_row][b_c4] = *(const float4*)(B + (size_t)(k0 + b_row) * ldb + bcol + b_c4);
    __syncthreads();
#pragma unroll
    for (int k = 0; k < 16; ++k) {
      float ra[4], rb[4];
#pragma unroll
      for (int i = 0; i < 4; ++i) ra[i] = As[k][tr * 4 + i];
#pragma unroll
      for (int j = 0; j < 4; ++j) rb[j] = Bs[k][tc * 4 + j];
#pragma unroll
      for (int i = 0; i < 4; ++i)
#pragma unroll
        for (int j = 0; j < 4; ++j) acc[i][j] = fmaf(ra[i], rb[j], acc[i][j]);
    }
    __syncthreads();
  }
  for (int i = 0; i < 4; ++i) {
    int row = brow + tr * 4 + i;
    for (int j = 0; j < 4; ++j) {
      int col = bcol + tc * 4 + j;
      float v = acc[i][j];
      if (bias) v += bias[col];
      C[(size_t)row * ldc + col] = v;
    }
  }
}

// ---------------------------------------------------------------- per-iter: Xw & h GEMM with U/V epilogue
// A = x (NEV x 256). cols 0..1023: Xw -> U=G1+Xw+b1, V=G2-Xw. cols 1024..1279: h = x@projW + projB.
__global__ __launch_bounds__(256) void k_uvh(
    const float* __restrict__ x, const float* __restrict__ W1c,
    const float* __restrict__ projW, const float* __restrict__ b1,
    const float* __restrict__ projB, const float* __restrict__ G1,
    const float* __restrict__ G2, float* __restrict__ U,
    float* __restrict__ V, float* __restrict__ h)
{
  __shared__ float As[16][68];
  __shared__ float Bs[16][68];
  int tid = threadIdx.x;
  int brow = blockIdx.y * 64;
  int bcol = blockIdx.x * 64;
  bool isH = (bcol >= MLPH);
  const float* B = isH ? (projW + (bcol - MLPH)) : (W1c + bcol);
  int ldb = isH ? CDIM : MLPH;
  int tr = tid >> 4;
  int tc = tid & 15;
  int a_row = tid >> 2;
  int a_c4  = (tid & 3) << 2;
  int b_row = tid >> 4;
  int b_c4  = (tid & 15) << 2;
  float acc[4][4] = {};
  for (int k0 = 0; k0 < CDIM; k0 += 16) {
    float4 av = *(const float4*)(x + (size_t)(brow + a_row) * CDIM + k0 + a_c4);
    As[a_c4 + 0][a_row] = av.x;
    As[a_c4 + 1][a_row] = av.y;
    As[a_c4 + 2][a_row] = av.z;
    As[a_c4 + 3][a_row] = av.w;
    *(float4*)&Bs[b_row][b_c4] = *(const float4*)(B + (size_t)(k0 + b_row) * ldb + b_c4);
    __syncthreads();
#pragma unroll
    for (int k = 0; k < 16; ++k) {
      float ra[4], rb[4];
#pragma unroll
      for (int i = 0; i < 4; ++i) ra[i] = As[k][tr * 4 + i];
#pragma unroll
      for (int j = 0; j < 4; ++j) rb[j] = Bs[k][tc * 4 + j];
#pragma unroll
      for (int i = 0; i < 4; ++i)
#pragma unroll
        for (int j = 0; j < 4; ++j) acc[i][j] = fmaf(ra[i], rb[j], acc[i][j]);
    }
    __syncthreads();
  }
  for (int i = 0; i < 4; ++i) {
    int row = brow + tr * 4 + i;
    for (int j = 0; j < 4; ++j) {
      int col = bcol + tc * 4 + j;
      float v = acc[i][j];
      if (isH) {
        int c = col - MLPH;
        h[(size_t)row * CDIM + c] = v + projB[c];
      } else {
        size_t idx = (size_t)row * MLPH + col;
        U[idx] = G1[idx] + v + b1[col];
        V[idx] = G2[idx] - v;
      }
    }
  }
}

// ---------------------------------------------------------------- per-node attention dots s = h . att
__global__ void k_s(const float* __restrict__ h,
                    const float* __restrict__ asi, const float* __restrict__ adi,
                    const float* __restrict__ asj, const float* __restrict__ adj,
                    float* __restrict__ sv) {
  int node = blockIdx.x * 4 + (threadIdx.x >> 6);
  int lane = threadIdx.x & 63;
  int head = lane >> 4;
  int d0 = (lane & 15) << 2;
  float4 hv = *(const float4*)(h + (size_t)node * CDIM + head * 64 + d0);
  float4 w1 = *(const float4*)(asi + head * 64 + d0);
  float4 w2 = *(const float4*)(adi + head * 64 + d0);
  float4 w3 = *(const float4*)(asj + head * 64 + d0);
  float4 w4 = *(const float4*)(adj + head * 64 + d0);
  float p1 = hv.x * w1.x + hv.y * w1.y + hv.z * w1.z + hv.w * w1.w;
  float p2 = hv.x * w2.x + hv.y * w2.y + hv.z * w2.z + hv.w * w2.w;
  float p3 = hv.x * w3.x + hv.y * w3.y + hv.z * w3.z + hv.w * w3.w;
  float p4 = hv.x * w4.x + hv.y * w4.y + hv.z * w4.z + hv.w * w4.w;
#pragma unroll
  for (int m = 1; m < 16; m <<= 1) {
    p1 += __shfl_xor(p1, m);
    p2 += __shfl_xor(p2, m);
    p3 += __shfl_xor(p3, m);
    p4 += __shfl_xor(p4, m);
  }
  if ((lane & 15) == 0) {
    sv[0 * NEV * 4 + node * 4 + head] = p1;
    sv[1 * NEV * 4 + node * 4 + head] = p2;
    sv[2 * NEV * 4 + node * 4 + head] = p3;
    sv[3 * NEV * 4 + node * 4 + head] = p4;
  }
}

// ---------------------------------------------------------------- pred / softmax / loss / masks (one wave per pair)
__global__ __launch_bounds__(256) void k_pred(
    const float* __restrict__ U, const float* __restrict__ V,
    const int* __restrict__ pair, const float* __restrict__ W2,
    const float* __restrict__ b2, const int* __restrict__ target,
    int* __restrict__ mstate, float* __restrict__ out,
    float* __restrict__ partials, float lossCoef)
{
  __shared__ float red[4];
  int wv = threadIdx.x >> 6;
  int p = blockIdx.x * 4 + wv;
  int lane = threadIdx.x & 63;
  int i0 = pair[2 * p], i1 = pair[2 * p + 1];
  const float* u = U + (size_t)i0 * MLPH;
  const float* v = V + (size_t)i1 * MLPH;
  float a0 = 0.f, a1 = 0.f, a2 = 0.f;
  for (int kb = (lane << 2); kb < MLPH; kb += 256) {
    float4 uu = *(const float4*)(u + kb);
    float4 vv = *(const float4*)(v + kb);
    float h0 = fmaxf(uu.x + vv.x, 0.f);
    float h1 = fmaxf(uu.y + vv.y, 0.f);
    float h2 = fmaxf(uu.z + vv.z, 0.f);
    float h3 = fmaxf(uu.w + vv.w, 0.f);
    const float4* w4 = (const float4*)(W2 + 3 * kb);
    float4 wa = w4[0], wb = w4[1], wc = w4[2];
    a0 += h0 * wa.x + h1 * wa.w + h2 * wb.z + h3 * wc.y;
    a1 += h0 * wa.y + h1 * wb.x + h2 * wb.w + h3 * wc.z;
    a2 += h0 * wa.z + h1 * wb.y + h2 * wc.x + h3 * wc.w;
  }
#pragma unroll
  for (int m = 32; m >= 1; m >>= 1) {
    a0 += __shfl_down(a0, m);
    a1 += __shfl_down(a1, m);
    a2 += __shfl_down(a2, m);
  }
  if (lane == 0) {
    a0 += b2[0]; a1 += b2[1]; a2 += b2[2];
    float mx = fmaxf(a0, fmaxf(a1, a2));
    float e0 = expf(a0 - mx), e1 = expf(a1 - mx), e2 = expf(a2 - mx);
    float sum = e0 + e1 + e2;
    int arg = 0; float best = e0;
    if (e1 > best) { best = e1; arg = 1; }
    if (e2 > best) { best = e2; arg = 2; }
    bool conf = (best / sum) > 0.5f;
    mstate[p] = conf ? arg : -1;
    int t = target[p];
    float predt = (t == 0) ? a0 : ((t == 1) ? a1 : a2);
    float logp = (predt - mx) - logf(sum);
    red[wv] = -logp * lossCoef;
    float* po = out + 1 + (size_t)p * 3;
    po[0] = a0; po[1] = a1; po[2] = a2;
  }
  __syncthreads();
  if (threadIdx.x == 0) partials[blockIdx.x] = red[0] + red[1] + red[2] + red[3];
}

__global__ void k_lossred(const float* __restrict__ partials, float* __restrict__ out, int n) {
  __shared__ float sm[256];
  float s = 0.f;
  for (int i = threadIdx.x; i < n; i += 256) s += partials[i];
  sm[threadIdx.x] = s;
  __syncthreads();
  for (int off = 128; off; off >>= 1) {
    if (threadIdx.x < off) sm[threadIdx.x] += sm[threadIdx.x + off];
    __syncthreads();
  }
  if (threadIdx.x == 0) out[0] += sm[0];
}

// ---------------------------------------------------------------- attention aggregate, one block per dst node
__global__ __launch_bounds__(256) void k_attn(
    const float* __restrict__ h, const float* __restrict__ sv,
    const int* __restrict__ rowp, const int* __restrict__ e_src,
    const int* __restrict__ e_id, const int* __restrict__ mstate,
    const int* __restrict__ rel, float* __restrict__ x)
{
  int node = blockIdx.x;
  int t = threadIdx.x;          // dim index 0..255 (head = t>>6)
  int head = t >> 6;
  const float* s_si = sv;
  const float* s_di = sv + NEV * 4;
  const float* s_sj = sv + 2 * NEV * 4;
  const float* s_dj = sv + 3 * NEV * 4;
  float sdi = s_di[node * 4 + head];
  float sdj = s_dj[node * 4 + head];
  int beg = rowp[node], end = rowp[node + 1];
  // self edge (intra, always unmasked)
  float aself = s_si[node * 4 + head] + sdi;
  aself = aself > 0.f ? aself : 0.2f * aself;
  float mxi = aself;
  float mxj = -1e9f;
  // pass 1: masked max per head
  for (int e = beg; e < end; ++e) {
    int eid = e_id[e];
    int pp = (eid < NPAIR) ? eid : eid - NPAIR;
    int st = mstate[pp];
    bool mall = (eid < NPAIR) ? (st == 1) : (st == 2);
    if (!mall) continue;
    int src = e_src[e];
    if (rel[pp] == 0) {
      float a = s_si[src * 4 + head] + sdi;
      a = a > 0.f ? a : 0.2f * a;
      mxi = fmaxf(mxi, a);
    } else {
      float a = s_sj[src * 4 + head] + sdj;
      a = a > 0.f ? a : 0.2f * a;
      mxj = fmaxf(mxj, a);
    }
  }
  // pass 2: exp-sum + weighted accumulate
  float deni = 0.f, denj = 0.f, acci = 0.f, accj = 0.f;
  {
    float ex = expf(aself - mxi);
    deni += ex;
    acci += ex * h[(size_t)node * CDIM + t];
  }
  for (int e = beg; e < end; ++e) {
    int eid = e_id[e];
    int pp = (eid < NPAIR) ? eid : eid - NPAIR;
    int st = mstate[pp];
    bool mall = (eid < NPAIR) ? (st == 1) : (st == 2);
    if (!mall) continue;
    int src = e_src[e];
    float hval = h[(size_t)src * CDIM + t];
    if (rel[pp] == 0) {
      float a = s_si[src * 4 + head] + sdi;
      a = a > 0.f ? a : 0.2f * a;
      float ex = expf(a - mxi);
      deni += ex; acci += ex * hval;
    } else {
      float a = s_sj[src * 4 + head] + sdj;
      a = a > 0.f ? a : 0.2f * a;
      float ex = expf(a - mxj);
      denj += ex; accj += ex * hval;
    }
  }
  float outv = 0.5f * (acci / (deni + 1e-9f)) + 0.5f * (accj / (denj + 1e-9f));
  x[(size_t)node * CDIM + t] = outv;
}

// ---------------------------------------------------------------- launch
extern "C" void kernel_launch(void* const* d_in, const int* in_sizes, int n_in,
                              void* d_out, int out_size, void* d_ws, size_t ws_size,
                              hipStream_t stream)
{
  const float* sent      = (const float*)d_in[0];
  const float* proj_in_W = (const float*)d_in[1];
  const float* proj_in_b = (const float*)d_in[2];
  const float* proj_W    = (const float*)d_in[3];
  const float* proj_b    = (const float*)d_in[4];
  const float* asi       = (const float*)d_in[5];
  const float* adi       = (const float*)d_in[6];
  const float* asj       = (const float*)d_in[7];
  const float* adj       = (const float*)d_in[8];
  const float* W1        = (const float*)d_in[9];
  const float* b1        = (const float*)d_in[10];
  const float* W2        = (const float*)d_in[11];
  const float* b2        = (const float*)d_in[12];
  const int*   es        = (const int*)d_in[13];
  const int*   st        = (const int*)d_in[14];
  const int*   en        = (const int*)d_in[15];
  const int*   pair      = (const int*)d_in[16];
  const int*   rel       = (const int*)d_in[17];
  const int*   target    = (const int*)d_in[18];
  float* out = (float*)d_out;

  char* w = (char*)d_ws;
  auto alloc = [&](size_t bytes) -> char* {
    char* p = w;
    w += (bytes + 255) & ~(size_t)255;
    return p;
  };
  float* e_emb  = (float*)alloc(sizeof(float) * (size_t)NEV * EDIM);
  float* G1     = (float*)alloc(sizeof(float) * (size_t)NEV * MLPH);
  float* G2     = (float*)alloc(sizeof(float) * (size_t)NEV * MLPH);
  float* U      = (float*)alloc(sizeof(float) * (size_t)NEV * MLPH);
  float* V      = (float*)alloc(sizeof(float) * (size_t)NEV * MLPH);
  float* x      = (float*)alloc(sizeof(float) * (size_t)NEV * CDIM);
  float* h      = (float*)alloc(sizeof(float) * (size_t)NEV * CDIM);
  float* sv     = (float*)alloc(sizeof(float) * (size_t)NEV * 16);
  float* lpart  = (float*)alloc(sizeof(float) * (NPAIR / 4));
  int* deg      = (int*)alloc(sizeof(int) * NEV);
  int* rowp     = (int*)alloc(sizeof(int) * (NEV + 1));
  int* cursor   = (int*)alloc(sizeof(int) * NEV);
  int* e_src    = (int*)alloc(sizeof(int) * NEDGE);
  int* e_id     = (int*)alloc(sizeof(int) * NEDGE);
  int* mstate   = (int*)alloc(sizeof(int) * NPAIR);

  k_zero<<<(NEV + 255) / 256, 256, 0, stream>>>(deg, out);
  k_embed<<<NEV, 256, 0, stream>>>(sent, es, st, en, e_emb);
  k_count<<<NEDGE / 256, 256, 0, stream>>>(pair, deg);
  k_scan<<<1, 256, 0, stream>>>(deg, rowp, cursor);
  k_scatter<<<NEDGE / 256, 256, 0, stream>>>(pair, rowp, cursor, e_src, e_id);

  // x0 = e_emb @ proj_in_W + b ; G1 = e_emb @ W1[0:768] ; G2 = e_emb @ W1[768:1536]
  {
    dim3 g(CDIM / 64, NEV / 64);
    sgemm64<<<g, 256, 0, stream>>>(e_emb, proj_in_W, x, proj_in_b, EDIM, EDIM, CDIM, CDIM);
  }
  {
    dim3 g(MLPH / 64, NEV / 64);
    sgemm64<<<g, 256, 0, stream>>>(e_emb, W1, G1, nullptr, EDIM, EDIM, MLPH, MLPH);
    sgemm64<<<g, 256, 0, stream>>>(e_emb, W1 + (size_t)EDIM * MLPH, G2, nullptr, EDIM, EDIM, MLPH, MLPH);
  }

  const float* W1c = W1 + (size_t)1536 * MLPH;  // diff rows
  for (int it = 0; it < 3; ++it) {
    dim3 gu((MLPH + CDIM) / 64, NEV / 64);
    k_uvh<<<gu, 256, 0, stream>>>(x, W1c, proj_W, b1, proj_b, G1, G2, U, V, h);
    k_s<<<NEV / 4, 256, 0, stream>>>(h, asi, adi, asj, adj, sv);
    float coef = 1.0f / ((float)(it + 1) * (float)NPAIR);
    k_pred<<<NPAIR / 4, 256, 0, stream>>>(U, V, pair, W2, b2, target, mstate, out, lpart, coef);
    k_lossred<<<1, 256, 0, stream>>>(lpart, out, NPAIR / 4);
    k_attn<<<NEV, 256, 0, stream>>>(h, sv, rowp, e_src, e_id, mstate, rel, x);
  }
  (void)in_sizes; (void)n_in; (void)out_size; (void)ws_size;
}

// Round 3
// 647.696 us; speedup vs baseline: 1.1617x; 1.1617x over previous
//
#include <hip/hip_runtime.h>
#include <cstddef>
#include <cstdint>

#define NEV   4096
#define NPAIR 32768
#define NEDGE (2*NPAIR)
#define EDIM  768
#define CDIM  256
#define MLPH  1024
#define LLEN  256

typedef unsigned short u16;
typedef __attribute__((ext_vector_type(8))) short bhalf8;
typedef __attribute__((ext_vector_type(4))) float f32x4;

__device__ inline u16 f2bf(float f) {
  union { float f; unsigned u; } v; v.f = f;
  unsigned r = v.u + 0x7fffu + ((v.u >> 16) & 1u);
  return (u16)(r >> 16);
}
__device__ inline float bf2f(u16 h) {
  union { unsigned u; float f; } v; v.u = ((unsigned)h) << 16; return v.f;
}

// ---------------------------------------------------------------- utilities
__global__ void k_zero(int* __restrict__ deg, float* __restrict__ out) {
  int i = blockIdx.x * 256 + threadIdx.x;
  if (i < NEV) deg[i] = 0;
  if (i == 0) out[0] = 0.f;
}

// ---------------------------------------------------------------- e_emb: masked span mean, fused bf16 hi/hi/lo split -> Ahat (NEV x 2304)
__global__ void k_embed(const float* __restrict__ sent, const int* __restrict__ es,
                        const int* __restrict__ st, const int* __restrict__ en,
                        u16* __restrict__ Ahat) {
  int node = blockIdx.x;
  int s = es[node];
  int a = st[node];
  int span = en[node] - a;
  float fspan = (float)span;
  const float* base = sent + ((size_t)s * LLEN + a) * EDIM;
  for (int d = threadIdx.x; d < EDIM; d += 256) {
    float acc = 0.f;
    for (int m = 0; m < span; ++m) acc += base[(size_t)m * EDIM + d];
    float e = acc / fspan;
    u16 hi = f2bf(e);
    float lo = e - bf2f(hi);
    size_t b = (size_t)node * (3 * EDIM);
    Ahat[b + d] = hi;
    Ahat[b + EDIM + d] = hi;
    Ahat[b + 2 * EDIM + d] = f2bf(lo);
  }
}

// ---------------------------------------------------------------- CSR build (dst_all = [p1; p0])
__global__ void k_count(const int* __restrict__ pair, int* __restrict__ deg) {
  int e = blockIdx.x * 256 + threadIdx.x;
  if (e >= NEDGE) return;
  int p = (e < NPAIR) ? e : e - NPAIR;
  int dst = (e < NPAIR) ? pair[2 * p + 1] : pair[2 * p];
  atomicAdd(&deg[dst], 1);
}

__global__ void k_scan(const int* __restrict__ deg, int* __restrict__ rowp,
                       int* __restrict__ cursor) {
  __shared__ int part[256];
  int t = threadIdx.x;
  int base = t * 16;
  int sum = 0;
  for (int i = 0; i < 16; ++i) sum += deg[base + i];
  part[t] = sum;
  __syncthreads();
  for (int off = 1; off < 256; off <<= 1) {
    int v = (t >= off) ? part[t - off] : 0;
    __syncthreads();
    part[t] += v;
    __syncthreads();
  }
  int run = (t == 0) ? 0 : part[t - 1];
  for (int i = 0; i < 16; ++i) {
    rowp[base + i] = run;
    cursor[base + i] = 0;
    run += deg[base + i];
  }
  if (t == 255) rowp[NEV] = run;
}

__global__ void k_scatter(const int* __restrict__ pair, const int* __restrict__ rowp,
                          int* __restrict__ cursor, int* __restrict__ e_src,
                          int* __restrict__ e_id) {
  int e = blockIdx.x * 256 + threadIdx.x;
  if (e >= NEDGE) return;
  int p   = (e < NPAIR) ? e : e - NPAIR;
  int src = (e < NPAIR) ? pair[2 * p]     : pair[2 * p + 1];
  int dst = (e < NPAIR) ? pair[2 * p + 1] : pair[2 * p];
  int pos = rowp[dst] + atomicAdd(&cursor[dst], 1);
  e_src[pos] = src;
  e_id[pos]  = e;
}

// ---------------------------------------------------------------- weight conversion: build B^T bf16 [Bh;Bl;Bh] planes, tiled transpose
// which=0: emb GEMM weights, K=768, N=2304 (cols: 0..1023 W1[0:768], 1024..2047 W1[768:1536], 2048..2303 proj_in_W)
// which=1: uvh GEMM weights, K=256, N=1280 (cols: 0..1023 W1[1536:1792], 1024..1279 proj_W)
__global__ __launch_bounds__(256) void cvt_w(const float* __restrict__ W1,
                                             const float* __restrict__ piW,
                                             const float* __restrict__ projW,
                                             u16* __restrict__ BT, int which)
{
  __shared__ float tile[32][33];
  int K = which ? CDIM : EDIM;
  int ld = K * 3;
  int bk = blockIdx.y * 32;
  int bc = blockIdx.x * 32;
  int tx = threadIdx.x & 31, ty = threadIdx.x >> 5;
#pragma unroll
  for (int rr = 0; rr < 4; ++rr) {
    int k = bk + ty + rr * 8;
    int c = bc + tx;
    float v;
    if (which == 0) {
      v = (c < 1024) ? W1[(size_t)k * MLPH + c]
        : (c < 2048) ? W1[(size_t)(EDIM + k) * MLPH + (c - 1024)]
        : piW[(size_t)k * CDIM + (c - 2048)];
    } else {
      v = (c < 1024) ? W1[(size_t)(2 * EDIM + k) * MLPH + c]
        : projW[(size_t)k * CDIM + (c - 1024)];
    }
    tile[ty + rr * 8][tx] = v;
  }
  __syncthreads();
#pragma unroll
  for (int rr = 0; rr < 4; ++rr) {
    int c = bc + ty + rr * 8;
    int k = bk + tx;
    float v = tile[tx][ty + rr * 8];
    u16 hi = f2bf(v);
    float lo = v - bf2f(hi);
    size_t b = (size_t)c * ld;
    BT[b + k] = hi;
    BT[b + K + k] = f2bf(lo);
    BT[b + 2 * K + k] = hi;
  }
}

// ---------------------------------------------------------------- bf16 MFMA GEMM, 128x128 tile, BK=64, 4 waves, 16x16x32 fragments
// A: M x Kp row-major bf16 ([Ah|Ah|Al]); BT: N x Kp row-major bf16 (B^T, [Bh;Bl;Bh])
// mode 0: N=2304; col<1024 -> G1, <2048 -> G2, else Xhat (x0 = C + pib, split hi/hi/lo)
// mode 1: N=1280; col<1024 -> U = G1 + C + b1, V = G2 - C ; else h = C + pb
__global__ __launch_bounds__(256) void mgemm(
    const u16* __restrict__ A, const u16* __restrict__ BT, int Kp, int mode,
    float* __restrict__ G1, float* __restrict__ G2, u16* __restrict__ Xhat,
    const float* __restrict__ pib, const float* __restrict__ b1,
    const float* __restrict__ pb, float* __restrict__ U, float* __restrict__ V,
    float* __restrict__ h)
{
  __shared__ u16 As[128 * 64];
  __shared__ u16 Bs[128 * 64];
  int tid = threadIdx.x;
  int wave = tid >> 6, lane = tid & 63;
  int bm = blockIdx.y * 128, bn = blockIdx.x * 128;
  int wm = (wave >> 1) * 64, wn = (wave & 1) * 64;

  int srow = tid >> 3;            // 0..31
  int scol = (tid & 7) << 3;      // 0,8,..,56 (bf16 elems)
  const u16* Ag = A + (size_t)(bm + srow) * Kp + scol;
  const u16* Bg = BT + (size_t)(bn + srow) * Kp + scol;

  f32x4 acc[4][4];
#pragma unroll
  for (int i = 0; i < 4; ++i)
#pragma unroll
    for (int j = 0; j < 4; ++j) {
      f32x4 z = {0.f, 0.f, 0.f, 0.f};
      acc[i][j] = z;
    }

  int fr = lane & 15;             // fragment row (A) / col (B,D)
  int fq = lane >> 4;             // k-group / D row-group

  for (int k0 = 0; k0 < Kp; k0 += 64) {
#pragma unroll
    for (int c = 0; c < 4; ++c) {
      uint4 av = *(const uint4*)(Ag + (size_t)(c * 32) * Kp);
      uint4 bv = *(const uint4*)(Bg + (size_t)(c * 32) * Kp);
      *(uint4*)&As[(c * 32 + srow) * 64 + scol] = av;
      *(uint4*)&Bs[(c * 32 + srow) * 64 + scol] = bv;
    }
    __syncthreads();
#pragma unroll
    for (int kk = 0; kk < 2; ++kk) {
      bhalf8 af[4], bf[4];
#pragma unroll
      for (int i = 0; i < 4; ++i)
        af[i] = *(const bhalf8*)&As[(wm + i * 16 + fr) * 64 + kk * 32 + fq * 8];
#pragma unroll
      for (int j = 0; j < 4; ++j)
        bf[j] = *(const bhalf8*)&Bs[(wn + j * 16 + fr) * 64 + kk * 32 + fq * 8];
#pragma unroll
      for (int i = 0; i < 4; ++i)
#pragma unroll
        for (int j = 0; j < 4; ++j)
          acc[i][j] = __builtin_amdgcn_mfma_f32_16x16x32_bf16(af[i], bf[j], acc[i][j], 0, 0, 0);
    }
    __syncthreads();
    Ag += 64;
    Bg += 64;
  }

#pragma unroll
  for (int i = 0; i < 4; ++i) {
    int mrow = bm + wm + i * 16 + fq * 4;
#pragma unroll
    for (int g = 0; g < 4; ++g) {
      int m = mrow + g;
#pragma unroll
      for (int j = 0; j < 4; ++j) {
        int c = bn + wn + j * 16 + fr;
        float vv = acc[i][j][g];
        if (mode == 0) {
          if (c < 1024) {
            G1[(size_t)m * MLPH + c] = vv;
          } else if (c < 2048) {
            G2[(size_t)m * MLPH + (c - 1024)] = vv;
          } else {
            int cc = c - 2048;
            float xv = vv + pib[cc];
            u16 hi = f2bf(xv);
            float lo = xv - bf2f(hi);
            size_t b = (size_t)m * (3 * CDIM);
            Xhat[b + cc] = hi;
            Xhat[b + CDIM + cc] = hi;
            Xhat[b + 2 * CDIM + cc] = f2bf(lo);
          }
        } else {
          if (c < 1024) {
            size_t idx = (size_t)m * MLPH + c;
            U[idx] = G1[idx] + vv + b1[c];
            V[idx] = G2[idx] - vv;
          } else {
            int cc = c - 1024;
            h[(size_t)m * CDIM + cc] = vv + pb[cc];
          }
        }
      }
    }
  }
}

// ---------------------------------------------------------------- per-node attention dots s = h . att
__global__ void k_s(const float* __restrict__ h,
                    const float* __restrict__ asi, const float* __restrict__ adi,
                    const float* __restrict__ asj, const float* __restrict__ adj,
                    float* __restrict__ sv) {
  int node = blockIdx.x * 4 + (threadIdx.x >> 6);
  int lane = threadIdx.x & 63;
  int head = lane >> 4;
  int d0 = (lane & 15) << 2;
  float4 hv = *(const float4*)(h + (size_t)node * CDIM + head * 64 + d0);
  float4 w1 = *(const float4*)(asi + head * 64 + d0);
  float4 w2 = *(const float4*)(adi + head * 64 + d0);
  float4 w3 = *(const float4*)(asj + head * 64 + d0);
  float4 w4 = *(const float4*)(adj + head * 64 + d0);
  float p1 = hv.x * w1.x + hv.y * w1.y + hv.z * w1.z + hv.w * w1.w;
  float p2 = hv.x * w2.x + hv.y * w2.y + hv.z * w2.z + hv.w * w2.w;
  float p3 = hv.x * w3.x + hv.y * w3.y + hv.z * w3.z + hv.w * w3.w;
  float p4 = hv.x * w4.x + hv.y * w4.y + hv.z * w4.z + hv.w * w4.w;
#pragma unroll
  for (int m = 1; m < 16; m <<= 1) {
    p1 += __shfl_xor(p1, m);
    p2 += __shfl_xor(p2, m);
    p3 += __shfl_xor(p3, m);
    p4 += __shfl_xor(p4, m);
  }
  if ((lane & 15) == 0) {
    sv[0 * NEV * 4 + node * 4 + head] = p1;
    sv[1 * NEV * 4 + node * 4 + head] = p2;
    sv[2 * NEV * 4 + node * 4 + head] = p3;
    sv[3 * NEV * 4 + node * 4 + head] = p4;
  }
}

// ---------------------------------------------------------------- pred / softmax / loss / masks (one wave per pair)
__global__ __launch_bounds__(256) void k_pred(
    const float* __restrict__ U, const float* __restrict__ V,
    const int* __restrict__ pair, const float* __restrict__ W2,
    const float* __restrict__ b2, const int* __restrict__ target,
    int* __restrict__ mstate, float* __restrict__ out,
    float* __restrict__ partials, float lossCoef)
{
  __shared__ float red[4];
  int wv = threadIdx.x >> 6;
  int p = blockIdx.x * 4 + wv;
  int lane = threadIdx.x & 63;
  int i0 = pair[2 * p], i1 = pair[2 * p + 1];
  const float* u = U + (size_t)i0 * MLPH;
  const float* v = V + (size_t)i1 * MLPH;
  float a0 = 0.f, a1 = 0.f, a2 = 0.f;
  for (int kb = (lane << 2); kb < MLPH; kb += 256) {
    float4 uu = *(const float4*)(u + kb);
    float4 vv = *(const float4*)(v + kb);
    float h0 = fmaxf(uu.x + vv.x, 0.f);
    float h1 = fmaxf(uu.y + vv.y, 0.f);
    float h2 = fmaxf(uu.z + vv.z, 0.f);
    float h3 = fmaxf(uu.w + vv.w, 0.f);
    const float4* w4 = (const float4*)(W2 + 3 * kb);
    float4 wa = w4[0], wb = w4[1], wc = w4[2];
    a0 += h0 * wa.x + h1 * wa.w + h2 * wb.z + h3 * wc.y;
    a1 += h0 * wa.y + h1 * wb.x + h2 * wb.w + h3 * wc.z;
    a2 += h0 * wa.z + h1 * wb.y + h2 * wc.x + h3 * wc.w;
  }
#pragma unroll
  for (int m = 32; m >= 1; m >>= 1) {
    a0 += __shfl_down(a0, m);
    a1 += __shfl_down(a1, m);
    a2 += __shfl_down(a2, m);
  }
  if (lane == 0) {
    a0 += b2[0]; a1 += b2[1]; a2 += b2[2];
    float mx = fmaxf(a0, fmaxf(a1, a2));
    float e0 = expf(a0 - mx), e1 = expf(a1 - mx), e2 = expf(a2 - mx);
    float sum = e0 + e1 + e2;
    int arg = 0; float best = e0;
    if (e1 > best) { best = e1; arg = 1; }
    if (e2 > best) { best = e2; arg = 2; }
    bool conf = (best / sum) > 0.5f;
    mstate[p] = conf ? arg : -1;
    int t = target[p];
    float predt = (t == 0) ? a0 : ((t == 1) ? a1 : a2);
    float logp = (predt - mx) - logf(sum);
    red[wv] = -logp * lossCoef;
    float* po = out + 1 + (size_t)p * 3;
    po[0] = a0; po[1] = a1; po[2] = a2;
  }
  __syncthreads();
  if (threadIdx.x == 0) partials[blockIdx.x] = red[0] + red[1] + red[2] + red[3];
}

__global__ void k_lossred(const float* __restrict__ partials, float* __restrict__ out, int n) {
  __shared__ float sm[256];
  float s = 0.f;
  for (int i = threadIdx.x; i < n; i += 256) s += partials[i];
  sm[threadIdx.x] = s;
  __syncthreads();
  for (int off = 128; off; off >>= 1) {
    if (threadIdx.x < off) sm[threadIdx.x] += sm[threadIdx.x + off];
    __syncthreads();
  }
  if (threadIdx.x == 0) out[0] += sm[0];
}

// ---------------------------------------------------------------- attention aggregate, one block per dst node; writes Xhat (bf16 hi/hi/lo)
__global__ __launch_bounds__(256) void k_attn(
    const float* __restrict__ h, const float* __restrict__ sv,
    const int* __restrict__ rowp, const int* __restrict__ e_src,
    const int* __restrict__ e_id, const int* __restrict__ mstate,
    const int* __restrict__ rel, u16* __restrict__ Xhat)
{
  int node = blockIdx.x;
  int t = threadIdx.x;          // dim index 0..255 (head = t>>6)
  int head = t >> 6;
  const float* s_si = sv;
  const float* s_di = sv + NEV * 4;
  const float* s_sj = sv + 2 * NEV * 4;
  const float* s_dj = sv + 3 * NEV * 4;
  float sdi = s_di[node * 4 + head];
  float sdj = s_dj[node * 4 + head];
  int beg = rowp[node], end = rowp[node + 1];
  float aself = s_si[node * 4 + head] + sdi;
  aself = aself > 0.f ? aself : 0.2f * aself;
  float mxi = aself;
  float mxj = -1e9f;
  for (int e = beg; e < end; ++e) {
    int eid = e_id[e];
    int pp = (eid < NPAIR) ? eid : eid - NPAIR;
    int st = mstate[pp];
    bool mall = (eid < NPAIR) ? (st == 1) : (st == 2);
    if (!mall) continue;
    int src = e_src[e];
    if (rel[pp] == 0) {
      float a = s_si[src * 4 + head] + sdi;
      a = a > 0.f ? a : 0.2f * a;
      mxi = fmaxf(mxi, a);
    } else {
      float a = s_sj[src * 4 + head] + sdj;
      a = a > 0.f ? a : 0.2f * a;
      mxj = fmaxf(mxj, a);
    }
  }
  float deni = 0.f, denj = 0.f, acci = 0.f, accj = 0.f;
  {
    float ex = expf(aself - mxi);
    deni += ex;
    acci += ex * h[(size_t)node * CDIM + t];
  }
  for (int e = beg; e < end; ++e) {
    int eid = e_id[e];
    int pp = (eid < NPAIR) ? eid : eid - NPAIR;
    int st = mstate[pp];
    bool mall = (eid < NPAIR) ? (st == 1) : (st == 2);
    if (!mall) continue;
    int src = e_src[e];
    float hval = h[(size_t)src * CDIM + t];
    if (rel[pp] == 0) {
      float a = s_si[src * 4 + head] + sdi;
      a = a > 0.f ? a : 0.2f * a;
      float ex = expf(a - mxi);
      deni += ex; acci += ex * hval;
    } else {
      float a = s_sj[src * 4 + head] + sdj;
      a = a > 0.f ? a : 0.2f * a;
      float ex = expf(a - mxj);
      denj += ex; accj += ex * hval;
    }
  }
  float outv = 0.5f * (acci / (deni + 1e-9f)) + 0.5f * (accj / (denj + 1e-9f));
  u16 hi = f2bf(outv);
  float lo = outv - bf2f(hi);
  size_t b = (size_t)node * (3 * CDIM);
  Xhat[b + t] = hi;
  Xhat[b + CDIM + t] = hi;
  Xhat[b + 2 * CDIM + t] = f2bf(lo);
}

// ---------------------------------------------------------------- launch
extern "C" void kernel_launch(void* const* d_in, const int* in_sizes, int n_in,
                              void* d_out, int out_size, void* d_ws, size_t ws_size,
                              hipStream_t stream)
{
  const float* sent      = (const float*)d_in[0];
  const float* proj_in_W = (const float*)d_in[1];
  const float* proj_in_b = (const float*)d_in[2];
  const float* proj_W    = (const float*)d_in[3];
  const float* proj_b    = (const float*)d_in[4];
  const float* asi       = (const float*)d_in[5];
  const float* adi       = (const float*)d_in[6];
  const float* asj       = (const float*)d_in[7];
  const float* adj       = (const float*)d_in[8];
  const float* W1        = (const float*)d_in[9];
  const float* b1        = (const float*)d_in[10];
  const float* W2        = (const float*)d_in[11];
  const float* b2        = (const float*)d_in[12];
  const int*   es        = (const int*)d_in[13];
  const int*   st        = (const int*)d_in[14];
  const int*   en        = (const int*)d_in[15];
  const int*   pair      = (const int*)d_in[16];
  const int*   rel       = (const int*)d_in[17];
  const int*   target    = (const int*)d_in[18];
  float* out = (float*)d_out;

  char* w = (char*)d_ws;
  auto alloc = [&](size_t bytes) -> char* {
    char* p = w;
    w += (bytes + 255) & ~(size_t)255;
    return p;
  };
  u16*   Ahat = (u16*)alloc(sizeof(u16) * (size_t)NEV * 3 * EDIM);      // 18.9 MB
  u16*   BTe  = (u16*)alloc(sizeof(u16) * (size_t)2304 * 2304);         // 10.6 MB
  u16*   BTu  = (u16*)alloc(sizeof(u16) * (size_t)1280 * 768);          //  2.0 MB
  u16*   Xhat = (u16*)alloc(sizeof(u16) * (size_t)NEV * 3 * CDIM);      //  6.3 MB
  float* G1   = (float*)alloc(sizeof(float) * (size_t)NEV * MLPH);
  float* G2   = (float*)alloc(sizeof(float) * (size_t)NEV * MLPH);
  float* U    = (float*)alloc(sizeof(float) * (size_t)NEV * MLPH);
  float* V    = (float*)alloc(sizeof(float) * (size_t)NEV * MLPH);
  float* h    = (float*)alloc(sizeof(float) * (size_t)NEV * CDIM);
  float* sv   = (float*)alloc(sizeof(float) * (size_t)NEV * 16);
  float* lpart= (float*)alloc(sizeof(float) * (NPAIR / 4));
  int* deg    = (int*)alloc(sizeof(int) * NEV);
  int* rowp   = (int*)alloc(sizeof(int) * (NEV + 1));
  int* cursor = (int*)alloc(sizeof(int) * NEV);
  int* e_src  = (int*)alloc(sizeof(int) * NEDGE);
  int* e_id   = (int*)alloc(sizeof(int) * NEDGE);
  int* mstate = (int*)alloc(sizeof(int) * NPAIR);

  k_zero<<<(NEV + 255) / 256, 256, 0, stream>>>(deg, out);
  k_embed<<<NEV, 256, 0, stream>>>(sent, es, st, en, Ahat);
  k_count<<<NEDGE / 256, 256, 0, stream>>>(pair, deg);
  k_scan<<<1, 256, 0, stream>>>(deg, rowp, cursor);
  k_scatter<<<NEDGE / 256, 256, 0, stream>>>(pair, rowp, cursor, e_src, e_id);

  // weight conversion (once per launch)
  cvt_w<<<dim3(2304 / 32, 768 / 32), 256, 0, stream>>>(W1, proj_in_W, proj_W, BTe, 0);
  cvt_w<<<dim3(1280 / 32, 256 / 32), 256, 0, stream>>>(W1, proj_in_W, proj_W, BTu, 1);

  // [G1 | G2 | x0] = e_emb @ [W1a | W1b | proj_in_W]  (bf16x3 via K'=3K)
  mgemm<<<dim3(2304 / 128, NEV / 128), 256, 0, stream>>>(
      Ahat, BTe, 3 * EDIM, 0, G1, G2, Xhat, proj_in_b,
      nullptr, nullptr, nullptr, nullptr, nullptr);

  for (int it = 0; it < 3; ++it) {
    // [Xw -> U,V | h] = x @ [W1c | proj_W]
    mgemm<<<dim3(1280 / 128, NEV / 128), 256, 0, stream>>>(
        Xhat, BTu, 3 * CDIM, 1, G1, G2, nullptr, nullptr,
        b1, proj_b, U, V, h);
    k_s<<<NEV / 4, 256, 0, stream>>>(h, asi, adi, asj, adj, sv);
    float coef = 1.0f / ((float)(it + 1) * (float)NPAIR);
    k_pred<<<NPAIR / 4, 256, 0, stream>>>(U, V, pair, W2, b2, target, mstate, out, lpart, coef);
    k_lossred<<<1, 256, 0, stream>>>(lpart, out, NPAIR / 4);
    k_attn<<<NEV, 256, 0, stream>>>(h, sv, rowp, e_src, e_id, mstate, rel, Xhat);
  }
  (void)in_sizes; (void)n_in; (void)out_size; (void)ws_size;
}